// Round 3
// baseline (479.216 us; speedup 1.0000x reference)
//
#include <hip/hip_runtime.h>

#define BB 512
#define SS 1024
#define TT 64

__device__ __forceinline__ float wsum64(float v) {
#pragma unroll
  for (int off = 32; off > 0; off >>= 1) v += __shfl_xor(v, off, 64);
  return v;
}

// X-macro list: apply M(i) for i = 0..63
#define E_LIST(M) \
  M(0) M(1) M(2) M(3) M(4) M(5) M(6) M(7) \
  M(8) M(9) M(10) M(11) M(12) M(13) M(14) M(15) \
  M(16) M(17) M(18) M(19) M(20) M(21) M(22) M(23) \
  M(24) M(25) M(26) M(27) M(28) M(29) M(30) M(31) \
  M(32) M(33) M(34) M(35) M(36) M(37) M(38) M(39) \
  M(40) M(41) M(42) M(43) M(44) M(45) M(46) M(47) \
  M(48) M(49) M(50) M(51) M(52) M(53) M(54) M(55) \
  M(56) M(57) M(58) M(59) M(60) M(61) M(62) M(63)

#define RLI(pb, i) __int_as_float(__builtin_amdgcn_readlane((pb), (i)))
#define RLF(v, i) __int_as_float(__builtin_amdgcn_readlane(__float_as_int(v), (i)))

// One 16-wide group of the 64-term dot product, for BOTH chains (A, B).
// Structure: [16 RL-A][16 RL-B][16 FMA-A][16 FMA-B] — every readlane's
// consuming FMA is >=16 instructions downstream (SGPR-write hazard buried),
// and the two chains' FMA dep-chains interleave for ILP.
// Accumulator assignment is i&3 — identical order to the verified kernel.
#define GRP16(I0, I1, I2, I3, I4, I5, I6, I7, I8, I9, I10, I11, I12, I13, I14, I15) \
  {                                                                                 \
    float rA0 = RLI(pbA, I0), rA1 = RLI(pbA, I1), rA2 = RLI(pbA, I2),               \
          rA3 = RLI(pbA, I3), rA4 = RLI(pbA, I4), rA5 = RLI(pbA, I5),               \
          rA6 = RLI(pbA, I6), rA7 = RLI(pbA, I7), rA8 = RLI(pbA, I8),               \
          rA9 = RLI(pbA, I9), rA10 = RLI(pbA, I10), rA11 = RLI(pbA, I11),           \
          rA12 = RLI(pbA, I12), rA13 = RLI(pbA, I13), rA14 = RLI(pbA, I14),         \
          rA15 = RLI(pbA, I15);                                                     \
    float rB0 = RLI(pbB, I0), rB1 = RLI(pbB, I1), rB2 = RLI(pbB, I2),               \
          rB3 = RLI(pbB, I3), rB4 = RLI(pbB, I4), rB5 = RLI(pbB, I5),               \
          rB6 = RLI(pbB, I6), rB7 = RLI(pbB, I7), rB8 = RLI(pbB, I8),               \
          rB9 = RLI(pbB, I9), rB10 = RLI(pbB, I10), rB11 = RLI(pbB, I11),           \
          rB12 = RLI(pbB, I12), rB13 = RLI(pbB, I13), rB14 = RLI(pbB, I14),         \
          rB15 = RLI(pbB, I15);                                                     \
    aA0 = fmaf(rA0, E##I0, aA0);                                                    \
    aA1 = fmaf(rA1, E##I1, aA1);                                                    \
    aA2 = fmaf(rA2, E##I2, aA2);                                                    \
    aA3 = fmaf(rA3, E##I3, aA3);                                                    \
    aA0 = fmaf(rA4, E##I4, aA0);                                                    \
    aA1 = fmaf(rA5, E##I5, aA1);                                                    \
    aA2 = fmaf(rA6, E##I6, aA2);                                                    \
    aA3 = fmaf(rA7, E##I7, aA3);                                                    \
    aA0 = fmaf(rA8, E##I8, aA0);                                                    \
    aA1 = fmaf(rA9, E##I9, aA1);                                                    \
    aA2 = fmaf(rA10, E##I10, aA2);                                                  \
    aA3 = fmaf(rA11, E##I11, aA3);                                                  \
    aA0 = fmaf(rA12, E##I12, aA0);                                                  \
    aA1 = fmaf(rA13, E##I13, aA1);                                                  \
    aA2 = fmaf(rA14, E##I14, aA2);                                                  \
    aA3 = fmaf(rA15, E##I15, aA3);                                                  \
    aB0 = fmaf(rB0, E##I0, aB0);                                                    \
    aB1 = fmaf(rB1, E##I1, aB1);                                                    \
    aB2 = fmaf(rB2, E##I2, aB2);                                                    \
    aB3 = fmaf(rB3, E##I3, aB3);                                                    \
    aB0 = fmaf(rB4, E##I4, aB0);                                                    \
    aB1 = fmaf(rB5, E##I5, aB1);                                                    \
    aB2 = fmaf(rB6, E##I6, aB2);                                                    \
    aB3 = fmaf(rB7, E##I7, aB3);                                                    \
    aB0 = fmaf(rB8, E##I8, aB0);                                                    \
    aB1 = fmaf(rB9, E##I9, aB1);                                                    \
    aB2 = fmaf(rB10, E##I10, aB2);                                                  \
    aB3 = fmaf(rB11, E##I11, aB3);                                                  \
    aB0 = fmaf(rB12, E##I12, aB0);                                                  \
    aB1 = fmaf(rB13, E##I13, aB1);                                                  \
    aB2 = fmaf(rB14, E##I14, aB2);                                                  \
    aB3 = fmaf(rB15, E##I15, aB3);                                                  \
  }

// One recurrence step for TWO independent same-direction chains (A, B).
// Linear domain, delayed scalar normalization — per-chain math is identical
// (bitwise) to the verified single-chain kernel:
// fwd (DIR=0): broadcast p; s_j = sum_i p_i E_ij ; p' = s * (f_j * inv)
// bwd (DIR=1): broadcast t_j = p_j * f_j * inv ; p'_i = sum_j E_ij t_j
// inv = 1/readfirstlane(s) from the PREVIOUS step (off critical path).
#define STEP_PAIR(eA, mkA, eB, mkB)                                                     \
  do {                                                                                  \
    float fA_ = __expf((eA) * (mkA));                                                   \
    float fB_ = __expf((eB) * (mkB));                                                   \
    float pvA_ = (DIR == 1) ? pA * (fA_ * invA) : pA;                                   \
    float pvB_ = (DIR == 1) ? pB * (fB_ * invB) : pB;                                   \
    int pbA = __float_as_int(pvA_);                                                     \
    int pbB = __float_as_int(pvB_);                                                     \
    float aA0 = 0.f, aA1 = 0.f, aA2 = 0.f, aA3 = 0.f;                                   \
    float aB0 = 0.f, aB1 = 0.f, aB2 = 0.f, aB3 = 0.f;                                   \
    GRP16(0, 1, 2, 3, 4, 5, 6, 7, 8, 9, 10, 11, 12, 13, 14, 15)                         \
    GRP16(16, 17, 18, 19, 20, 21, 22, 23, 24, 25, 26, 27, 28, 29, 30, 31)               \
    GRP16(32, 33, 34, 35, 36, 37, 38, 39, 40, 41, 42, 43, 44, 45, 46, 47)               \
    GRP16(48, 49, 50, 51, 52, 53, 54, 55, 56, 57, 58, 59, 60, 61, 62, 63)               \
    float sA_ = (aA0 + aA1) + (aA2 + aA3);                                              \
    float sB_ = (aB0 + aB1) + (aB2 + aB3);                                              \
    pA = (DIR == 0) ? sA_ * (fA_ * invA) : sA_;                                         \
    pB = (DIR == 0) ? sB_ * (fB_ * invB) : sB_;                                         \
    float rnA_ = __int_as_float(__builtin_amdgcn_readfirstlane(__float_as_int(sA_)));   \
    float rnB_ = __int_as_float(__builtin_amdgcn_readfirstlane(__float_as_int(sB_)));   \
    invA = __builtin_amdgcn_rcpf(rnA_);                                                 \
    invB = __builtin_amdgcn_rcpf(rnB_);                                                 \
    float lgA_ = __logf(rnA_);                                                          \
    float lgB_ = __logf(rnB_);                                                          \
    LaccA += lgA_;                                                                      \
    LaccB += lgB_;                                                                      \
    lastlgA = lgA_;                                                                     \
    lastlgB = lgB_;                                                                     \
  } while (0)

template <int DIR>
__device__ __forceinline__ void part_pair(int b0, int b1, int lane,
                                          const float* __restrict__ em,
                                          const float* __restrict__ mask,
                                          const float* __restrict__ trans,
                                          float* __restrict__ outv) {
  // Shared E fragment (same direction => same layout for both chains):
  // fwd lane j holds column E[i][j]; bwd lane i holds row E[i][j].
  // 64 NAMED scalars — never an array -> never scratch.
  const float* tp = trans + (DIR == 0 ? lane : lane * TT);
#define EINIT(i) float E##i = __expf((DIR == 0) ? tp[(i)*TT] : tp[(i)]);
  E_LIST(EINIT)
#undef EINIT

  const float* embA = em + (size_t)b0 * SS * TT;
  const float* embB = em + (size_t)b1 * SS * TT;
  const float* mkbA = mask + (size_t)b0 * SS;
  const float* mkbB = mask + (size_t)b1 * SS;

  constexpr int NST = (DIR == 0) ? (SS / 2 - 1) : (SS / 2);  // 511 fwd, 512 bwd
  constexpr int S0 = (DIR == 0) ? 1 : (SS - 1);
  constexpr int SD = (DIR == 0) ? 1 : -1;
  constexpr int NG8 = NST / 8;    // full groups of 8 steps
  constexpr int TAIL8 = NST & 7;  // 7 fwd, 0 bwd

  float pA = (DIR == 0) ? __expf(embA[lane] * mkbA[0]) : 1.0f;
  float pB = (DIR == 0) ? __expf(embB[lane] * mkbB[0]) : 1.0f;
  float invA = 1.0f, invB = 1.0f;
  float LaccA = 0.0f, LaccB = 0.0f, lastlgA = 0.0f, lastlgB = 0.0f;

  // 8-deep emission prefetch per chain (coalesced: lane j reads em[b][s][j])
  float ebufA[8], ebufB[8];
#pragma unroll
  for (int k = 0; k < 8; ++k) {
    ebufA[k] = embA[(S0 + SD * k) * TT + lane];
    ebufB[k] = embB[(S0 + SD * k) * TT + lane];
  }
  const float* epA = embA + (ptrdiff_t)(S0 + SD * 8) * TT + lane;
  const float* epB = embB + (ptrdiff_t)(S0 + SD * 8) * TT + lane;

  // mask: one coalesced vector load per 64 steps per chain, broadcast via readlane
  float mvA = 0.f, mvB = 0.f;
  for (int t8 = 0; t8 < NG8; ++t8) {
    if ((t8 & 7) == 0) {
      mvA = mkbA[S0 + SD * (t8 * 8 + lane)];
      mvB = mkbB[S0 + SD * (t8 * 8 + lane)];
    }
    const int base = (t8 & 7) * 8;
#pragma unroll
    for (int k = 0; k < 8; ++k) {
      float eA = ebufA[k];
      float eB = ebufB[k];
      ebufA[k] = *epA;  // prefetch step t+8; in-bounds (fwd s<=519, bwd s>=504)
      ebufB[k] = *epB;
      epA += SD * TT;
      epB += SD * TT;
      float mkA = RLF(mvA, base + k);
      float mkB = RLF(mvB, base + k);
      STEP_PAIR(eA, mkA, eB, mkB);
    }
  }
  if constexpr (TAIL8 > 0) {  // fwd only
#pragma unroll
    for (int k = 0; k < TAIL8; ++k) {
      float eA = ebufA[k];
      float eB = ebufB[k];
      float mkA = RLF(mvA, (NG8 & 7) * 8 + k);
      float mkB = RLF(mvB, (NG8 & 7) * 8 + k);
      STEP_PAIR(eA, mkA, eB, mkB);
    }
  }

  outv[b0 * TT + lane] = __logf(pA) + (LaccA - lastlgA);
  outv[b1 * TT + lane] = __logf(pB) + (LaccB - lastlgB);
}

// Fused: blocks [0, 512) = partition, each wave runs TWO same-direction chains
//        (even bid: fwd pair -> alpha; odd bid: bwd pair -> beta);
//        blocks [512, 2560) = gold score.
__global__ void __launch_bounds__(64, 1)
    fused_kernel(const float* __restrict__ em, const int* __restrict__ tags,
                 const float* __restrict__ mask, const float* __restrict__ trans,
                 float* __restrict__ alpha, float* __restrict__ beta,
                 float* __restrict__ gpart) {
  const int lane = threadIdx.x;
  const int bid = blockIdx.x;
  if (bid < BB) {
    const int q = bid >> 1;  // pair index 0..255
    const int b0 = 2 * q, b1 = 2 * q + 1;
    if ((bid & 1) == 0)
      part_pair<0>(b0, b1, lane, em, mask, trans, alpha);
    else
      part_pair<1>(b0, b1, lane, em, mask, trans, beta);
  } else {
    const int gid = bid - BB;  // 0..2047
    const int b = gid >> 2, q = gid & 3;
    const int* tg = tags + b * SS;
    const float* mkb = mask + (size_t)b * SS;
    const float* emb = em + (size_t)b * SS * TT;
    float part = 0.f;
#pragma unroll
    for (int i = 0; i < 4; ++i) {
      int s = q * 256 + i * 64 + lane;
      int t1 = tg[s];
      float e = emb[s * TT + t1];
      float contrib = (s == 0) ? e : (trans[t1 * TT + tg[s - 1]] + e);
      part = fmaf(contrib, mkb[s], part);
    }
    part = wsum64(part);
    if (lane == 0) gpart[gid] = part;
  }
}

// Single block, 512 threads: thread b computes Z_b - gold_b, block-reduces, writes mean.
__global__ void combine_kernel(const float* __restrict__ alpha, const float* __restrict__ beta,
                               const float* __restrict__ gpart, float* __restrict__ out) {
  const int b = threadIdx.x;  // 0..511
  const float* av = alpha + b * TT;
  const float* bv = beta + b * TT;
  float m = -3.4e38f, s = 0.f;
#pragma unroll 8
  for (int j = 0; j < TT; ++j) {
    float v = av[j] + bv[j];
    float nm = fmaxf(m, v);
    s = s * __expf(m - nm) + __expf(v - nm);
    m = nm;
  }
  float Z = m + __logf(s);
  float g = gpart[4 * b] + gpart[4 * b + 1] + gpart[4 * b + 2] + gpart[4 * b + 3];
  float val = Z - g;
  val = wsum64(val);
  __shared__ float red[8];
  if ((threadIdx.x & 63) == 0) red[threadIdx.x >> 6] = val;
  __syncthreads();
  if (threadIdx.x == 0) {
    float t = 0.f;
#pragma unroll
    for (int w = 0; w < 8; ++w) t += red[w];
    out[0] = t * (1.0f / (float)BB);
  }
}

extern "C" void kernel_launch(void* const* d_in, const int* in_sizes, int n_in,
                              void* d_out, int out_size, void* d_ws, size_t ws_size,
                              hipStream_t stream) {
  const float* em = (const float*)d_in[0];
  const int* tags = (const int*)d_in[1];
  const float* mask = (const float*)d_in[2];
  const float* trans = (const float*)d_in[3];
  float* out = (float*)d_out;

  float* alpha = (float*)d_ws;      // 512*64
  float* beta = alpha + BB * TT;    // 512*64
  float* gpart = beta + BB * TT;    // 2048

  fused_kernel<<<BB + 4 * BB, TT, 0, stream>>>(em, tags, mask, trans, alpha, beta, gpart);
  combine_kernel<<<1, BB, 0, stream>>>(alpha, beta, gpart, out);
}

// Round 4
// 346.126 us; speedup vs baseline: 1.3845x; 1.3845x over previous
//
#include <hip/hip_runtime.h>

#define BB 512
#define SS 1024
#define TT 64

__device__ __forceinline__ float wsum64(float v) {
#pragma unroll
  for (int off = 32; off > 0; off >>= 1) v += __shfl_xor(v, off, 64);
  return v;
}

// X-macro list: apply M(i) for i = 0..63
#define E_LIST(M) \
  M(0) M(1) M(2) M(3) M(4) M(5) M(6) M(7) \
  M(8) M(9) M(10) M(11) M(12) M(13) M(14) M(15) \
  M(16) M(17) M(18) M(19) M(20) M(21) M(22) M(23) \
  M(24) M(25) M(26) M(27) M(28) M(29) M(30) M(31) \
  M(32) M(33) M(34) M(35) M(36) M(37) M(38) M(39) \
  M(40) M(41) M(42) M(43) M(44) M(45) M(46) M(47) \
  M(48) M(49) M(50) M(51) M(52) M(53) M(54) M(55) \
  M(56) M(57) M(58) M(59) M(60) M(61) M(62) M(63)

#define RLS(i) __builtin_amdgcn_readlane(pb_, (i))
#define RLF(v, i) __int_as_float(__builtin_amdgcn_readlane(__float_as_int(v), (i)))

// Pinned-class FMA: acc(VGPR) += broadcast(SGPR, from readlane) * E(VGPR).
// The "v" constraint on E forces its live range into arch VGPRs — prevents
// the AGPR-parking (v_accvgpr_read per use) seen at VGPR_Count=52.
// Same op as fmaf -> bitwise-identical result.
#define AFMA(acc, r, Ev) \
  asm("v_fma_f32 %0, %1, %2, %0" : "+v"(acc) : "s"(r), "v"(Ev));

// Readlane software-pipelined 4 ahead: each AFMA's SGPR operand was written
// >=4 instructions earlier (hazard wait-states buried).
// Accumulator mapping is i&3 — identical order to the verified round-0 kernel.
#define QSTEP(iA, iB, iC, iD, jA, jB, jC, jD) \
  AFMA(a0, r0, E##iA) r0 = RLS(jA);           \
  AFMA(a1, r1, E##iB) r1 = RLS(jB);           \
  AFMA(a2, r2, E##iC) r2 = RLS(jC);           \
  AFMA(a3, r3, E##iD) r3 = RLS(jD);

#define QLAST(iA, iB, iC, iD) \
  AFMA(a0, r0, E##iA)         \
  AFMA(a1, r1, E##iB)         \
  AFMA(a2, r2, E##iC)         \
  AFMA(a3, r3, E##iD)

#define FMA_ALL_PIPE                                        \
  int r0 = RLS(0), r1 = RLS(1), r2 = RLS(2), r3 = RLS(3);   \
  QSTEP(0, 1, 2, 3, 4, 5, 6, 7)                             \
  QSTEP(4, 5, 6, 7, 8, 9, 10, 11)                           \
  QSTEP(8, 9, 10, 11, 12, 13, 14, 15)                       \
  QSTEP(12, 13, 14, 15, 16, 17, 18, 19)                     \
  QSTEP(16, 17, 18, 19, 20, 21, 22, 23)                     \
  QSTEP(20, 21, 22, 23, 24, 25, 26, 27)                     \
  QSTEP(24, 25, 26, 27, 28, 29, 30, 31)                     \
  QSTEP(28, 29, 30, 31, 32, 33, 34, 35)                     \
  QSTEP(32, 33, 34, 35, 36, 37, 38, 39)                     \
  QSTEP(36, 37, 38, 39, 40, 41, 42, 43)                     \
  QSTEP(40, 41, 42, 43, 44, 45, 46, 47)                     \
  QSTEP(44, 45, 46, 47, 48, 49, 50, 51)                     \
  QSTEP(48, 49, 50, 51, 52, 53, 54, 55)                     \
  QSTEP(52, 53, 54, 55, 56, 57, 58, 59)                     \
  QSTEP(56, 57, 58, 59, 60, 61, 62, 63)                     \
  QLAST(60, 61, 62, 63)

// One recurrence step, linear domain, delayed scalar normalization.
// fwd (DIR=0): broadcast p; s_j = sum_i p_i E_ij ; p' = s * (f_j * inv)
// bwd (DIR=1): broadcast t_j = p_j * f_j * inv ; p'_i = sum_j E_ij t_j
// inv = 1/readfirstlane(s) from the PREVIOUS step (off critical path).
#define CRF_STEP(ev, mkv)                                                           \
  do {                                                                              \
    float f_ = __expf((ev) * (mkv));                                                \
    float pv_ = (DIR == 1) ? p * (f_ * inv) : p;                                    \
    int pb_ = __float_as_int(pv_);                                                  \
    float a0 = 0.f, a1 = 0.f, a2 = 0.f, a3 = 0.f;                                   \
    FMA_ALL_PIPE                                                                    \
    float s_ = (a0 + a1) + (a2 + a3);                                               \
    p = (DIR == 0) ? s_ * (f_ * inv) : s_;                                          \
    float rn_ = __int_as_float(__builtin_amdgcn_readfirstlane(__float_as_int(s_))); \
    inv = __builtin_amdgcn_rcpf(rn_);                                               \
    float lg_ = __logf(rn_);                                                        \
    Lacc += lg_;                                                                    \
    lastlg = lg_;                                                                   \
  } while (0)

template <int DIR>
__device__ __forceinline__ void part_run(int b, int lane, const float* __restrict__ em,
                                         const float* __restrict__ mask,
                                         const float* __restrict__ trans,
                                         float* __restrict__ outv) {
  // Per-lane E fragment as 64 NAMED scalars (never an array -> never scratch).
  // fwd lane j holds column E[i][j]; bwd lane i holds row E[i][j].
  const float* tp = trans + (DIR == 0 ? lane : lane * TT);
#define EINIT(i) float E##i = __expf((DIR == 0) ? tp[(i)*TT] : tp[(i)]);
  E_LIST(EINIT)
#undef EINIT

  const float* emb = em + (size_t)b * SS * TT;
  const float* mkb = mask + (size_t)b * SS;

  constexpr int NST = (DIR == 0) ? (SS / 2 - 1) : (SS / 2);  // 511 fwd, 512 bwd
  constexpr int S0 = (DIR == 0) ? 1 : (SS - 1);
  constexpr int SD = (DIR == 0) ? 1 : -1;
  constexpr int NG8 = NST / 8;    // full groups of 8 steps
  constexpr int TAIL8 = NST & 7;  // 7 fwd, 0 bwd

  float p = (DIR == 0) ? __expf(emb[lane] * mkb[0]) : 1.0f;
  float inv = 1.0f, Lacc = 0.0f, lastlg = 0.0f;

  // 8-deep emission prefetch (coalesced: lane j reads em[b][s][j])
  float ebuf[8];
#pragma unroll
  for (int k = 0; k < 8; ++k) ebuf[k] = emb[(S0 + SD * k) * TT + lane];
  const float* ep = emb + (ptrdiff_t)(S0 + SD * 8) * TT + lane;

  // mask: one coalesced vector load per 64-step window, prefetched ONE WINDOW
  // (64 steps) ahead so the load is never consumed in the same iteration.
  float mv = mkb[S0 + SD * lane];  // window 0
  float mvn = 0.f;
  for (int t8 = 0; t8 < NG8; ++t8) {
    if ((t8 & 7) == 0 && t8 != 0) mv = mvn;  // enter window t8>>3
    if ((t8 & 7) == 5)                       // prefetch window (t8>>3)+1
      mvn = mkb[S0 + SD * (((t8 >> 3) + 1) * 64 + lane)];
    const int base = (t8 & 7) * 8;
#pragma unroll
    for (int k = 0; k < 8; ++k) {
      float e = ebuf[k];
      ebuf[k] = *ep;  // prefetch step t+8; always in-bounds (fwd s<=519, bwd s>=504)
      ep += SD * TT;
      float mk = RLF(mv, base + k);
      CRF_STEP(e, mk);
    }
  }
  if constexpr (TAIL8 > 0) {  // fwd only: steps 504..510, window 7
#pragma unroll
    for (int k = 0; k < TAIL8; ++k) {
      float e = ebuf[k];
      float mk = RLF(mv, (NG8 & 7) * 8 + k);
      CRF_STEP(e, mk);
    }
  }

  outv[b * TT + lane] = __logf(p) + (Lacc - lastlg);
}

// Fused: blocks [0, 1024) = partition fwd/bwd; blocks [1024, 3072) = gold score
__global__ void __launch_bounds__(64, 1)
    fused_kernel(const float* __restrict__ em, const int* __restrict__ tags,
                 const float* __restrict__ mask, const float* __restrict__ trans,
                 float* __restrict__ alpha, float* __restrict__ beta,
                 float* __restrict__ gpart) {
  const int lane = threadIdx.x;
  const int bid = blockIdx.x;
  if (bid < 2 * BB) {
    const int b = bid >> 1;
    if ((bid & 1) == 0)
      part_run<0>(b, lane, em, mask, trans, alpha);
    else
      part_run<1>(b, lane, em, mask, trans, beta);
  } else {
    const int gid = bid - 2 * BB;  // 0..2047
    const int b = gid >> 2, q = gid & 3;
    const int* tg = tags + b * SS;
    const float* mkb = mask + (size_t)b * SS;
    const float* emb = em + (size_t)b * SS * TT;
    float part = 0.f;
#pragma unroll
    for (int i = 0; i < 4; ++i) {
      int s = q * 256 + i * 64 + lane;
      int t1 = tg[s];
      float e = emb[s * TT + t1];
      float contrib = (s == 0) ? e : (trans[t1 * TT + tg[s - 1]] + e);
      part = fmaf(contrib, mkb[s], part);
    }
    part = wsum64(part);
    if (lane == 0) gpart[gid] = part;
  }
}

// Single block, 512 threads: thread b computes Z_b - gold_b, block-reduces, writes mean.
__global__ void combine_kernel(const float* __restrict__ alpha, const float* __restrict__ beta,
                               const float* __restrict__ gpart, float* __restrict__ out) {
  const int b = threadIdx.x;  // 0..511
  const float* av = alpha + b * TT;
  const float* bv = beta + b * TT;
  float m = -3.4e38f, s = 0.f;
#pragma unroll 8
  for (int j = 0; j < TT; ++j) {
    float v = av[j] + bv[j];
    float nm = fmaxf(m, v);
    s = s * __expf(m - nm) + __expf(v - nm);
    m = nm;
  }
  float Z = m + __logf(s);
  float g = gpart[4 * b] + gpart[4 * b + 1] + gpart[4 * b + 2] + gpart[4 * b + 3];
  float val = Z - g;
  val = wsum64(val);
  __shared__ float red[8];
  if ((threadIdx.x & 63) == 0) red[threadIdx.x >> 6] = val;
  __syncthreads();
  if (threadIdx.x == 0) {
    float t = 0.f;
#pragma unroll
    for (int w = 0; w < 8; ++w) t += red[w];
    out[0] = t * (1.0f / (float)BB);
  }
}

extern "C" void kernel_launch(void* const* d_in, const int* in_sizes, int n_in,
                              void* d_out, int out_size, void* d_ws, size_t ws_size,
                              hipStream_t stream) {
  const float* em = (const float*)d_in[0];
  const int* tags = (const int*)d_in[1];
  const float* mask = (const float*)d_in[2];
  const float* trans = (const float*)d_in[3];
  float* out = (float*)d_out;

  float* alpha = (float*)d_ws;      // 512*64
  float* beta = alpha + BB * TT;    // 512*64
  float* gpart = beta + BB * TT;    // 2048

  fused_kernel<<<2 * BB + 4 * BB, TT, 0, stream>>>(em, tags, mask, trans, alpha, beta, gpart);
  combine_kernel<<<1, BB, 0, stream>>>(alpha, beta, gpart, out);
}

// Round 5
// 330.988 us; speedup vs baseline: 1.4478x; 1.0457x over previous
//
#include <hip/hip_runtime.h>

#define BB 512
#define SS 1024
#define TT 64

__device__ __forceinline__ float wsum64(float v) {
#pragma unroll
  for (int off = 32; off > 0; off >>= 1) v += __shfl_xor(v, off, 64);
  return v;
}

// X-macro list: apply M(i) for i = 0..63
#define E_LIST(M) \
  M(0) M(1) M(2) M(3) M(4) M(5) M(6) M(7) \
  M(8) M(9) M(10) M(11) M(12) M(13) M(14) M(15) \
  M(16) M(17) M(18) M(19) M(20) M(21) M(22) M(23) \
  M(24) M(25) M(26) M(27) M(28) M(29) M(30) M(31) \
  M(32) M(33) M(34) M(35) M(36) M(37) M(38) M(39) \
  M(40) M(41) M(42) M(43) M(44) M(45) M(46) M(47) \
  M(48) M(49) M(50) M(51) M(52) M(53) M(54) M(55) \
  M(56) M(57) M(58) M(59) M(60) M(61) M(62) M(63)

#define RLS(i) __builtin_amdgcn_readlane(pb_, (i))
#define RLF(v, i) __int_as_float(__builtin_amdgcn_readlane(__float_as_int(v), (i)))

// Banked readlane grouping (plain C — compiler keeps scheduling freedom).
// Bank of 8 broadcasts loaded while the OTHER bank's 8 FMAs execute:
// every readlane's consuming FMA is >=8-16 instructions downstream, so the
// VALU-writes-SGPR -> VALU-reads-SGPR wait states are buried (this grouping
// measured ~307 issue-cyc/step in the round-3 variant vs ~530 ungrouped).
#define LD8(B, j0, j1, j2, j3, j4, j5, j6, j7) \
  B##0 = RLS(j0);                              \
  B##1 = RLS(j1);                              \
  B##2 = RLS(j2);                              \
  B##3 = RLS(j3);                              \
  B##4 = RLS(j4);                              \
  B##5 = RLS(j5);                              \
  B##6 = RLS(j6);                              \
  B##7 = RLS(j7);

// FMA order i ascending, accumulator = i&3 — identical to the verified
// round-0 kernel => bitwise-identical sums.
#define FM8(B, i0, i1, i2, i3, i4, i5, i6, i7)    \
  a0 = fmaf(__int_as_float(B##0), E##i0, a0);     \
  a1 = fmaf(__int_as_float(B##1), E##i1, a1);     \
  a2 = fmaf(__int_as_float(B##2), E##i2, a2);     \
  a3 = fmaf(__int_as_float(B##3), E##i3, a3);     \
  a0 = fmaf(__int_as_float(B##4), E##i4, a0);     \
  a1 = fmaf(__int_as_float(B##5), E##i5, a1);     \
  a2 = fmaf(__int_as_float(B##6), E##i6, a2);     \
  a3 = fmaf(__int_as_float(B##7), E##i7, a3);

#define FMA_ALL_G                                  \
  int t0, t1, t2, t3, t4, t5, t6, t7;              \
  int u0, u1, u2, u3, u4, u5, u6, u7;              \
  LD8(t, 0, 1, 2, 3, 4, 5, 6, 7)                   \
  LD8(u, 8, 9, 10, 11, 12, 13, 14, 15)             \
  FM8(t, 0, 1, 2, 3, 4, 5, 6, 7)                   \
  LD8(t, 16, 17, 18, 19, 20, 21, 22, 23)           \
  FM8(u, 8, 9, 10, 11, 12, 13, 14, 15)             \
  LD8(u, 24, 25, 26, 27, 28, 29, 30, 31)           \
  FM8(t, 16, 17, 18, 19, 20, 21, 22, 23)           \
  LD8(t, 32, 33, 34, 35, 36, 37, 38, 39)           \
  FM8(u, 24, 25, 26, 27, 28, 29, 30, 31)           \
  LD8(u, 40, 41, 42, 43, 44, 45, 46, 47)           \
  FM8(t, 32, 33, 34, 35, 36, 37, 38, 39)           \
  LD8(t, 48, 49, 50, 51, 52, 53, 54, 55)           \
  FM8(u, 40, 41, 42, 43, 44, 45, 46, 47)           \
  LD8(u, 56, 57, 58, 59, 60, 61, 62, 63)           \
  FM8(t, 48, 49, 50, 51, 52, 53, 54, 55)           \
  FM8(u, 56, 57, 58, 59, 60, 61, 62, 63)

// One recurrence step, linear domain, delayed scalar normalization.
// fwd (DIR=0): broadcast p; s_j = sum_i p_i E_ij ; p' = s * (f_j * inv)
// bwd (DIR=1): broadcast t_j = p_j * f_j * inv ; p'_i = sum_j E_ij t_j
// inv = 1/readfirstlane(s) from the PREVIOUS step (off critical path).
#define CRF_STEP(ev, mkv)                                                           \
  do {                                                                              \
    float f_ = __expf((ev) * (mkv));                                                \
    float pv_ = (DIR == 1) ? p * (f_ * inv) : p;                                    \
    int pb_ = __float_as_int(pv_);                                                  \
    float a0 = 0.f, a1 = 0.f, a2 = 0.f, a3 = 0.f;                                   \
    FMA_ALL_G                                                                       \
    float s_ = (a0 + a1) + (a2 + a3);                                               \
    p = (DIR == 0) ? s_ * (f_ * inv) : s_;                                          \
    float rn_ = __int_as_float(__builtin_amdgcn_readfirstlane(__float_as_int(s_))); \
    inv = __builtin_amdgcn_rcpf(rn_);                                               \
    float lg_ = __logf(rn_);                                                        \
    Lacc += lg_;                                                                    \
    lastlg = lg_;                                                                   \
  } while (0)

template <int DIR>
__device__ __forceinline__ void part_run(int b, int lane, const float* __restrict__ em,
                                         const float* __restrict__ mask,
                                         const float* __restrict__ trans,
                                         float* __restrict__ outv) {
  // Per-lane E fragment as 64 NAMED scalars (never an array -> never scratch).
  // fwd lane j holds column E[i][j]; bwd lane i holds row E[i][j].
  const float* tp = trans + (DIR == 0 ? lane : lane * TT);
#define EINIT(i) float E##i = __expf((DIR == 0) ? tp[(i)*TT] : tp[(i)]);
  E_LIST(EINIT)
#undef EINIT

  const float* emb = em + (size_t)b * SS * TT;
  const float* mkb = mask + (size_t)b * SS;

  constexpr int NST = (DIR == 0) ? (SS / 2 - 1) : (SS / 2);  // 511 fwd, 512 bwd
  constexpr int S0 = (DIR == 0) ? 1 : (SS - 1);
  constexpr int SD = (DIR == 0) ? 1 : -1;
  constexpr int NG8 = NST / 8;    // full groups of 8 steps
  constexpr int TAIL8 = NST & 7;  // 7 fwd, 0 bwd

  float p = (DIR == 0) ? __expf(emb[lane] * mkb[0]) : 1.0f;
  float inv = 1.0f, Lacc = 0.0f, lastlg = 0.0f;

  // 8-deep emission prefetch (coalesced: lane j reads em[b][s][j])
  float ebuf[8];
#pragma unroll
  for (int k = 0; k < 8; ++k) ebuf[k] = emb[(S0 + SD * k) * TT + lane];
  const float* ep = emb + (ptrdiff_t)(S0 + SD * 8) * TT + lane;

  // mask: one coalesced vector load per 64-step window, prefetched ONE WINDOW
  // (64 steps) ahead so the load is never consumed in the same iteration.
  float mv = mkb[S0 + SD * lane];  // window 0
  float mvn = 0.f;
  for (int t8 = 0; t8 < NG8; ++t8) {
    if ((t8 & 7) == 0 && t8 != 0) mv = mvn;  // enter window t8>>3
    if ((t8 & 7) == 5)                       // prefetch window (t8>>3)+1
      mvn = mkb[S0 + SD * (((t8 >> 3) + 1) * 64 + lane)];
    const int base = (t8 & 7) * 8;
#pragma unroll
    for (int k = 0; k < 8; ++k) {
      float e = ebuf[k];
      ebuf[k] = *ep;  // prefetch step t+8; always in-bounds (fwd s<=519, bwd s>=504)
      ep += SD * TT;
      float mk = RLF(mv, base + k);
      CRF_STEP(e, mk);
    }
  }
  if constexpr (TAIL8 > 0) {  // fwd only: steps 504..510, window 7
#pragma unroll
    for (int k = 0; k < TAIL8; ++k) {
      float e = ebuf[k];
      float mk = RLF(mv, (NG8 & 7) * 8 + k);
      CRF_STEP(e, mk);
    }
  }

  outv[b * TT + lane] = __logf(p) + (Lacc - lastlg);
}

// Fused: blocks [0, 1024) = partition fwd/bwd; blocks [1024, 3072) = gold score
__global__ void __launch_bounds__(64, 1)
    fused_kernel(const float* __restrict__ em, const int* __restrict__ tags,
                 const float* __restrict__ mask, const float* __restrict__ trans,
                 float* __restrict__ alpha, float* __restrict__ beta,
                 float* __restrict__ gpart) {
  const int lane = threadIdx.x;
  const int bid = blockIdx.x;
  if (bid < 2 * BB) {
    const int b = bid >> 1;
    if ((bid & 1) == 0)
      part_run<0>(b, lane, em, mask, trans, alpha);
    else
      part_run<1>(b, lane, em, mask, trans, beta);
  } else {
    const int gid = bid - 2 * BB;  // 0..2047
    const int b = gid >> 2, q = gid & 3;
    const int* tg = tags + b * SS;
    const float* mkb = mask + (size_t)b * SS;
    const float* emb = em + (size_t)b * SS * TT;
    float part = 0.f;
#pragma unroll
    for (int i = 0; i < 4; ++i) {
      int s = q * 256 + i * 64 + lane;
      int t1 = tg[s];
      float e = emb[s * TT + t1];
      float contrib = (s == 0) ? e : (trans[t1 * TT + tg[s - 1]] + e);
      part = fmaf(contrib, mkb[s], part);
    }
    part = wsum64(part);
    if (lane == 0) gpart[gid] = part;
  }
}

// Single block, 512 threads: thread b computes Z_b - gold_b, block-reduces, writes mean.
__global__ void combine_kernel(const float* __restrict__ alpha, const float* __restrict__ beta,
                               const float* __restrict__ gpart, float* __restrict__ out) {
  const int b = threadIdx.x;  // 0..511
  const float* av = alpha + b * TT;
  const float* bv = beta + b * TT;
  float m = -3.4e38f, s = 0.f;
#pragma unroll 8
  for (int j = 0; j < TT; ++j) {
    float v = av[j] + bv[j];
    float nm = fmaxf(m, v);
    s = s * __expf(m - nm) + __expf(v - nm);
    m = nm;
  }
  float Z = m + __logf(s);
  float g = gpart[4 * b] + gpart[4 * b + 1] + gpart[4 * b + 2] + gpart[4 * b + 3];
  float val = Z - g;
  val = wsum64(val);
  __shared__ float red[8];
  if ((threadIdx.x & 63) == 0) red[threadIdx.x >> 6] = val;
  __syncthreads();
  if (threadIdx.x == 0) {
    float t = 0.f;
#pragma unroll
    for (int w = 0; w < 8; ++w) t += red[w];
    out[0] = t * (1.0f / (float)BB);
  }
}

extern "C" void kernel_launch(void* const* d_in, const int* in_sizes, int n_in,
                              void* d_out, int out_size, void* d_ws, size_t ws_size,
                              hipStream_t stream) {
  const float* em = (const float*)d_in[0];
  const int* tags = (const int*)d_in[1];
  const float* mask = (const float*)d_in[2];
  const float* trans = (const float*)d_in[3];
  float* out = (float*)d_out;

  float* alpha = (float*)d_ws;      // 512*64
  float* beta = alpha + BB * TT;    // 512*64
  float* gpart = beta + BB * TT;    // 2048

  fused_kernel<<<2 * BB + 4 * BB, TT, 0, stream>>>(em, tags, mask, trans, alpha, beta, gpart);
  combine_kernel<<<1, BB, 0, stream>>>(alpha, beta, gpart, out);
}